// Round 6
// baseline (213.101 us; speedup 1.0000x reference)
//
#include <hip/hip_runtime.h>

// ButterflyRotation: 12 butterfly layers over rows of 4096 fp32.
// R6: persistent pipelined blocks. 1024 blocks x 4 row-pairs; next pair's x
// prefetched into registers (coalesced) a full iteration early; ds_write to
// swizzled LDS; raw s_barrier with lgkm-only drain so global loads/stores
// stay in flight across barriers. Angle table in R5's transposed layout.
//   phase A: thread t owns e = 16t+k               -> layers 0-3
//   phase B: thread t owns e = 256(t&15)+16m+(t>>4) -> layers 4-7
//   phase C: thread t owns e = t+256m              -> layers 8-11

#define DIM    4096
#define LAYERS 12
#define BATCH  8192
#define NANG   2048
#define PAIRS  4               // row-pairs per block
#define GRID   (BATCH / 2 / PAIRS)

// raw barrier: drain LDS ops only; global loads/stores stay in flight
#define BAR() do {                                             \
    asm volatile("s_waitcnt lgkmcnt(0)" ::: "memory");         \
    __builtin_amdgcn_sched_barrier(0);                         \
    __builtin_amdgcn_s_barrier();                              \
} while (0)

// quad-level swizzle (involution: only bits 0-2 change)
__device__ __forceinline__ int swzQ(int Q) {
    return Q ^ ((Q >> 3) & 7) ^ ((Q >> 6) & 7);
}
// element -> swizzled LDS slot
__device__ __forceinline__ int perm(int e) {
    return (swzQ(e >> 2) << 2) | (e & 3);
}
// butterfly angle sub-index for left element m at level j (stride 2^j)
__device__ __forceinline__ constexpr int inner_idx(int m, int j) {
    return ((m >> (j + 1)) << j) + (m & ((1 << j) - 1));
}

__device__ __forceinline__ void rot(float& xl, float& xr, float c, float s) {
    float nl = fmaf(s, xr, c * xl);
    float nr = fmaf(-s, xl, c * xr);
    xl = nl; xr = nr;
}

// Transposed cos/sin table (same as R5):
//  region A (f4 [0,4096)):     layer l,   thread t, k2 -> angles 8t+2k2(+1)
//  region B (f4 [4096,8192)):  layer 4+j: angles 128(t&15)+(t>>4)+16*(2k2(+1))
//  region C (f4 [8192,12288)): layer 8+j: angles t+256*(2k2(+1))
__global__ void __launch_bounds__(256) cs_kernel(const float* __restrict__ angles,
                                                 float2* __restrict__ T, int n) {
    int i = blockIdx.x * blockDim.x + threadIdx.x;
    if (i >= n) return;
    float a = angles[i];
    float c = cosf(a), s = sinf(a);
    int l = i >> 11, aa = i & 2047;
    int f4, half;
    if (l < 4) {
        int t = aa >> 3, k = aa & 7;
        f4 = (l * 4 + (k >> 1)) * 256 + t; half = k & 1;
    } else if (l < 8) {
        int hi = aa >> 7, k = (aa >> 4) & 7, lo = aa & 15;
        int t = hi + (lo << 4);
        f4 = 4096 + ((l - 4) * 4 + (k >> 1)) * 256 + t; half = k & 1;
    } else {
        int k = aa >> 8, t = aa & 255;
        f4 = 8192 + ((l - 8) * 4 + (k >> 1)) * 256 + t; half = k & 1;
    }
    T[f4 * 2 + half] = make_float2(c, s);
}

__global__ void __launch_bounds__(256, 4)
butterfly_kernel(const float* __restrict__ x, const float4* __restrict__ T4,
                 float* __restrict__ out) {
    __shared__ float lds[2 * DIM];          // 32 KiB: row0 | row1
    const int t = threadIdx.x;
    const long pair0 = (long)blockIdx.x * PAIRS;

    float4 X0[4], X1[4];                    // prefetched next-pair x (e = 4t+1024m+k)
    {
        const float* s0 = x + pair0 * 2 * DIM + 4 * t;
        #pragma unroll
        for (int m = 0; m < 4; ++m) {
            X0[m] = *(const float4*)(s0 + 1024 * m);
            X1[m] = *(const float4*)(s0 + DIM + 1024 * m);
        }
    }
    asm volatile("s_waitcnt vmcnt(0)" ::: "memory");

    #pragma unroll 1
    for (int it = 0; it < PAIRS; ++it) {
        // ---- barrier a: previous iteration's phase-C LDS reads are done ----
        BAR();
        // drain the 8 prefetch loads (oldest); leave <=32 stores in flight
        asm volatile("s_waitcnt vmcnt(32)" ::: "memory");
        #pragma unroll
        for (int m = 0; m < 4; ++m) {
            *(float4*)(lds + 4 * swzQ(t + 256 * m))       = X0[m];
            *(float4*)(lds + DIM + 4 * swzQ(t + 256 * m)) = X1[m];
        }
        BAR();  // barrier b: stage writes -> phase A reads

        // ================= phase A: e = 16t + k =================
        float a0[16], a1[16];
        int pa[4];
        #pragma unroll
        for (int q = 0; q < 4; ++q) {
            pa[q] = 4 * swzQ(4 * t + q);
            float4 v0 = *(const float4*)(lds + pa[q]);
            float4 v1 = *(const float4*)(lds + DIM + pa[q]);
            a0[4*q+0] = v0.x; a0[4*q+1] = v0.y; a0[4*q+2] = v0.z; a0[4*q+3] = v0.w;
            a1[4*q+0] = v1.x; a1[4*q+1] = v1.y; a1[4*q+2] = v1.z; a1[4*q+3] = v1.w;
        }
        #pragma unroll
        for (int l = 0; l < 4; ++l) {
            const float4 A[4] = {T4[(l*4+0)*256 + t], T4[(l*4+1)*256 + t],
                                 T4[(l*4+2)*256 + t], T4[(l*4+3)*256 + t]};
            const int st = 1 << l;
            #pragma unroll
            for (int m = 0; m < 16; ++m) {
                if (!(m & st)) {
                    const int ai = inner_idx(m, l);
                    const float c = (ai & 1) ? A[ai>>1].z : A[ai>>1].x;
                    const float s = (ai & 1) ? A[ai>>1].w : A[ai>>1].y;
                    rot(a0[m], a0[m + st], c, s);
                    rot(a1[m], a1[m + st], c, s);
                }
            }
        }
        #pragma unroll
        for (int q = 0; q < 4; ++q) {
            *(float4*)(lds + pa[q])       = make_float4(a0[4*q], a0[4*q+1], a0[4*q+2], a0[4*q+3]);
            *(float4*)(lds + DIM + pa[q]) = make_float4(a1[4*q], a1[4*q+1], a1[4*q+2], a1[4*q+3]);
        }

        // ---- issue next pair's x loads; they fly across the next barriers ----
        if (it + 1 < PAIRS) {
            const float* s0 = x + (pair0 + it + 1) * 2 * DIM + 4 * t;
            #pragma unroll
            for (int m = 0; m < 4; ++m) {
                X0[m] = *(const float4*)(s0 + 1024 * m);
                X1[m] = *(const float4*)(s0 + DIM + 1024 * m);
            }
        }
        BAR();  // barrier c: phase A writeback -> phase B reads

        // ================= phase B: e = 256*hi + 16*m + lo =================
        const int hi = t & 15, lo = t >> 4;
        float d0[16], d1[16];
        int pb[16];
        #pragma unroll
        for (int m = 0; m < 16; ++m) {
            pb[m] = perm((hi << 8) + (m << 4) + lo);
            d0[m] = lds[pb[m]];
            d1[m] = lds[DIM + pb[m]];
        }
        #pragma unroll
        for (int j = 0; j < 4; ++j) {
            const float4 B[4] = {T4[4096 + (j*4+0)*256 + t], T4[4096 + (j*4+1)*256 + t],
                                 T4[4096 + (j*4+2)*256 + t], T4[4096 + (j*4+3)*256 + t]};
            const int st = 1 << j;
            #pragma unroll
            for (int m = 0; m < 16; ++m) {
                if (!(m & st)) {
                    const int ai = inner_idx(m, j);
                    const float c = (ai & 1) ? B[ai>>1].z : B[ai>>1].x;
                    const float s = (ai & 1) ? B[ai>>1].w : B[ai>>1].y;
                    rot(d0[m], d0[m + st], c, s);
                    rot(d1[m], d1[m + st], c, s);
                }
            }
        }
        #pragma unroll
        for (int m = 0; m < 16; ++m) {
            lds[pb[m]]       = d0[m];
            lds[DIM + pb[m]] = d1[m];
        }
        BAR();  // barrier d: phase B writeback -> phase C reads

        // ================= phase C: e = t + 256*m =================
        float g0[16], g1[16];
        #pragma unroll
        for (int m = 0; m < 16; ++m) {
            const int p = perm(t + (m << 8));
            g0[m] = lds[p];
            g1[m] = lds[DIM + p];
        }
        #pragma unroll
        for (int j = 0; j < 4; ++j) {
            const float4 C[4] = {T4[8192 + (j*4+0)*256 + t], T4[8192 + (j*4+1)*256 + t],
                                 T4[8192 + (j*4+2)*256 + t], T4[8192 + (j*4+3)*256 + t]};
            const int st = 1 << j;
            #pragma unroll
            for (int m = 0; m < 16; ++m) {
                if (!(m & st)) {
                    const int ai = inner_idx(m, j);
                    const float c = (ai & 1) ? C[ai>>1].z : C[ai>>1].x;
                    const float s = (ai & 1) ? C[ai>>1].w : C[ai>>1].y;
                    rot(g0[m], g0[m + st], c, s);
                    rot(g1[m], g1[m + st], c, s);
                }
            }
        }
        {
            float* o0 = out + (pair0 + it) * 2 * DIM + t;
            float* o1 = o0 + DIM;
            #pragma unroll
            for (int m = 0; m < 16; ++m) {
                o0[m << 8] = g0[m];
                o1[m << 8] = g1[m];
            }
        }
    }
}

extern "C" void kernel_launch(void* const* d_in, const int* in_sizes, int n_in,
                              void* d_out, int out_size, void* d_ws, size_t ws_size,
                              hipStream_t stream) {
    (void)in_sizes; (void)n_in; (void)out_size; (void)ws_size;
    const float* x      = (const float*)d_in[0];
    const float* angles = (const float*)d_in[1];
    float* out = (float*)d_out;

    const int n = LAYERS * NANG;                    // 24576 angles, 192 KiB table
    cs_kernel<<<(n + 255) / 256, 256, 0, stream>>>(angles, (float2*)d_ws, n);
    butterfly_kernel<<<GRID, 256, 0, stream>>>(x, (const float4*)d_ws, out);
}

// Round 7
// 61.216 us; speedup vs baseline: 3.4811x; 3.4811x over previous
//
#include <hip/hip_runtime.h>

// ButterflyRotation: 12 butterfly layers over rows of 4096 fp32.
// R7: R5 skeleton (grid 4096, dispatch-ordered streaming, 2 rows/block,
// 32 KiB LDS) re-tuned for occupancy: block=512 (8 waves), radix-8 x 4
// phases, VGPR<=64 -> 32 waves/CU. Angle table in 4-region transposed
// layout so every angle load is lane-contiguous.
//   P1: e = 8t+m                    -> layers 0-2
//   P2: e = 64(t>>3)+8m+(t&7)       -> layers 3-5
//   P3: e = 512(t>>6)+64m+(t&63)    -> layers 6-8
//   P4: e = t+512m                  -> layers 9-11
// Angle index per phase: a = base(t) + scale*inner_idx(m,jj).

#define DIM    4096
#define LAYERS 12
#define BATCH  8192
#define NANG   2048
#define BLOCK  512

typedef unsigned int u32;

// quad-level swizzle (involution: only bits 0-2 change)
__device__ __forceinline__ int swzQ(int Q) {
    return Q ^ ((Q >> 3) & 7) ^ ((Q >> 6) & 7);
}
// element -> swizzled LDS slot
__device__ __forceinline__ int perm(int e) {
    return (swzQ(e >> 2) << 2) | (e & 3);
}
// butterfly sub-index for left element m at local level jj (stride 2^jj)
__device__ __forceinline__ constexpr int inner_idx(int m, int jj) {
    return ((m >> (jj + 1)) << jj) + (m & ((1 << jj) - 1));
}

__device__ __forceinline__ void rot(float& xl, float& xr, float c, float s) {
    float nl = fmaf(s, xr, c * xl);
    float nr = fmaf(-s, xl, c * xr);
    xl = nl; xr = nr;
}

// Transposed table: 4 regions x 3 layers x 2 k2 x 512 threads of float4
// (each float4 = (c,s) for ii=2k2 and ii=2k2+1). 12288 float4 = 192 KiB.
__global__ void __launch_bounds__(256) cs_kernel(const float* __restrict__ angles,
                                                 float2* __restrict__ T, int n) {
    int i = blockIdx.x * blockDim.x + threadIdx.x;
    if (i >= n) return;
    float a = angles[i];
    float c = cosf(a), s = sinf(a);
    int l = i >> 11, aa = i & 2047;
    int region, jj, t, ii;
    if (l < 3)      { region = 0; jj = l;     t = aa >> 2;  ii = aa & 3; }
    else if (l < 6) { region = 1; jj = l - 3; int B = aa >> 5, r = aa & 31;
                      ii = r >> 3; t = 8 * B + (r & 7); }
    else if (l < 9) { region = 2; jj = l - 6; int S = aa >> 8, r = aa & 255;
                      ii = r >> 6; t = 64 * S + (r & 63); }
    else            { region = 3; jj = l - 9; ii = aa >> 9; t = aa & 511; }
    int f4 = region * 3072 + (jj * 2 + (ii >> 1)) * 512 + t;
    T[f4 * 2 + (ii & 1)] = make_float2(c, s);
}

// apply 3 layers (local strides 1,2,4) on v0/v1[8] with angle regs A[6]
#define PHASE_ROTS(A, v0, v1)                                              \
    _Pragma("unroll")                                                      \
    for (int jj = 0; jj < 3; ++jj) {                                       \
        const int st = 1 << jj;                                            \
        _Pragma("unroll")                                                  \
        for (int m = 0; m < 8; ++m) {                                      \
            if (!(m & st)) {                                               \
                const int ii = inner_idx(m, jj);                           \
                const float c = (ii & 1) ? A[jj*2+(ii>>1)].z : A[jj*2+(ii>>1)].x; \
                const float s = (ii & 1) ? A[jj*2+(ii>>1)].w : A[jj*2+(ii>>1)].y; \
                rot(v0[m], v0[m + st], c, s);                              \
                rot(v1[m], v1[m + st], c, s);                              \
            }                                                              \
        }                                                                  \
    }

__global__ void __launch_bounds__(BLOCK, 8)
butterfly_kernel(const float* __restrict__ x, const float4* __restrict__ T4,
                 float* __restrict__ out) {
    __shared__ float lds[2 * DIM];          // 32 KiB: row0 | row1
    const int t = threadIdx.x;
    const int wave = t >> 6, lane = t & 63;
    const long row0 = (long)blockIdx.x * 2;

    // ---- stage: linear LDS dest (wave-uniform base), swizzled global src ----
    #pragma unroll
    for (int r = 0; r < 2; ++r) {
        const float* src = x + (row0 + r) * DIM;
        #pragma unroll
        for (int m = 0; m < 2; ++m) {
            const int qbase = 512 * m + 64 * wave;         // wave-uniform
            const int g = swzQ(qbase + lane);              // logical quad for slot
            __builtin_amdgcn_global_load_lds(
                (const __attribute__((address_space(1))) u32*)(src + 4 * g),
                (__attribute__((address_space(3))) u32*)(lds + r * DIM + 4 * qbase),
                16, 0, 0);
        }
    }
    __syncthreads();

    float v0[8], v1[8];

    // ================= P1: e = 8t + m, layers 0-2 =================
    {
        const int q0 = 4 * swzQ(2 * t), q1 = 4 * swzQ(2 * t + 1);
        float4 A[6];
        #pragma unroll
        for (int k = 0; k < 6; ++k) A[k] = T4[k * 512 + t];
        float4 a00 = *(const float4*)(lds + q0);
        float4 a01 = *(const float4*)(lds + q1);
        float4 a10 = *(const float4*)(lds + DIM + q0);
        float4 a11 = *(const float4*)(lds + DIM + q1);
        v0[0]=a00.x; v0[1]=a00.y; v0[2]=a00.z; v0[3]=a00.w;
        v0[4]=a01.x; v0[5]=a01.y; v0[6]=a01.z; v0[7]=a01.w;
        v1[0]=a10.x; v1[1]=a10.y; v1[2]=a10.z; v1[3]=a10.w;
        v1[4]=a11.x; v1[5]=a11.y; v1[6]=a11.z; v1[7]=a11.w;
        PHASE_ROTS(A, v0, v1);
        *(float4*)(lds + q0)       = make_float4(v0[0], v0[1], v0[2], v0[3]);
        *(float4*)(lds + q1)       = make_float4(v0[4], v0[5], v0[6], v0[7]);
        *(float4*)(lds + DIM + q0) = make_float4(v1[0], v1[1], v1[2], v1[3]);
        *(float4*)(lds + DIM + q1) = make_float4(v1[4], v1[5], v1[6], v1[7]);
    }
    __syncthreads();

    // ================= P2: e = 64(t>>3) + 8m + (t&7), layers 3-5 =================
    {
        const int eb = 64 * (t >> 3) + (t & 7);
        float4 A[6];
        #pragma unroll
        for (int k = 0; k < 6; ++k) A[k] = T4[3072 + k * 512 + t];
        int ps[8];
        #pragma unroll
        for (int m = 0; m < 8; ++m) {
            ps[m] = perm(eb + 8 * m);
            v0[m] = lds[ps[m]];
            v1[m] = lds[DIM + ps[m]];
        }
        PHASE_ROTS(A, v0, v1);
        #pragma unroll
        for (int m = 0; m < 8; ++m) {
            lds[ps[m]]       = v0[m];
            lds[DIM + ps[m]] = v1[m];
        }
    }
    __syncthreads();

    // ================= P3: e = 512(t>>6) + 64m + (t&63), layers 6-8 =================
    {
        const int eb = 512 * (t >> 6) + (t & 63);
        float4 A[6];
        #pragma unroll
        for (int k = 0; k < 6; ++k) A[k] = T4[6144 + k * 512 + t];
        int ps[8];
        #pragma unroll
        for (int m = 0; m < 8; ++m) {
            ps[m] = perm(eb + 64 * m);
            v0[m] = lds[ps[m]];
            v1[m] = lds[DIM + ps[m]];
        }
        PHASE_ROTS(A, v0, v1);
        #pragma unroll
        for (int m = 0; m < 8; ++m) {
            lds[ps[m]]       = v0[m];
            lds[DIM + ps[m]] = v1[m];
        }
    }
    __syncthreads();

    // ================= P4: e = t + 512m, layers 9-11; store =================
    {
        float4 A[6];
        #pragma unroll
        for (int k = 0; k < 6; ++k) A[k] = T4[9216 + k * 512 + t];
        #pragma unroll
        for (int m = 0; m < 8; ++m) {
            const int p = perm(t + 512 * m);
            v0[m] = lds[p];
            v1[m] = lds[DIM + p];
        }
        PHASE_ROTS(A, v0, v1);
        float* o0 = out + row0 * DIM + t;
        float* o1 = o0 + DIM;
        #pragma unroll
        for (int m = 0; m < 8; ++m) {
            o0[m << 9] = v0[m];
            o1[m << 9] = v1[m];
        }
    }
}

extern "C" void kernel_launch(void* const* d_in, const int* in_sizes, int n_in,
                              void* d_out, int out_size, void* d_ws, size_t ws_size,
                              hipStream_t stream) {
    (void)in_sizes; (void)n_in; (void)out_size; (void)ws_size;
    const float* x      = (const float*)d_in[0];
    const float* angles = (const float*)d_in[1];
    float* out = (float*)d_out;

    const int n = LAYERS * NANG;                    // 24576 angles, 192 KiB table
    cs_kernel<<<(n + 255) / 256, 256, 0, stream>>>(angles, (float2*)d_ws, n);
    butterfly_kernel<<<BATCH / 2, BLOCK, 0, stream>>>(x, (const float4*)d_ws, out);
}